// Round 6
// baseline (108.852 us; speedup 1.0000x reference)
//
#include <hip/hip_runtime.h>

#define NB 8
#define TAPS 5

// antireflect column fetch
__device__ __forceinline__ float ldc(const float* __restrict__ row, int j, int N) {
    if ((unsigned)j < (unsigned)N) return row[j];
    const int e  = (j < 0) ? 0 : (N - 1);
    const int rr = (j < 0) ? -j : (2 * (N - 1) - j);
    return 2.f * row[e] - row[rr];
}
// antireflect row+column fetch
__device__ __forceinline__ float ldrc(const float* __restrict__ plane, int m, int j, int N) {
    if ((unsigned)m < (unsigned)N) return ldc(plane + (size_t)m * N, j, N);
    const int e  = (m < 0) ? 0 : (N - 1);
    const int rm = (m < 0) ? -m : (2 * (N - 1) - m);
    return 2.f * ldc(plane + (size_t)e * N, j, N) - ldc(plane + (size_t)rm * N, j, N);
}
__device__ __forceinline__ void fma4(float4& a, float c, const float4& v) {
    a.x += c * v.x; a.y += c * v.y; a.z += c * v.z; a.w += c * v.w;
}
// barrier that waits LDS ops but does NOT drain vmcnt (keeps prefetch loads in flight)
__device__ __forceinline__ void barrier_lgkm() {
    asm volatile("s_waitcnt lgkmcnt(0)" ::: "memory");
    __builtin_amdgcn_s_barrier();
}

// ---------------- pipelined row-band kernel (levels 0,1) ----------------
// Block: TW output cols x (G*32) output rows. Per 32-row group:
//   A) global->reg loads for next window  B) vertical synth from LDS buf
//   C) lgkm-barrier  D) horizontal synth + store  E) reg->LDS write next buf  F) barrier
template<int TW, int G>
__global__ __launch_bounds__(256)
void idwt_pipe(const float* __restrict__ Ass, const float* __restrict__ Asd,
               const float* __restrict__ Ads, const float* __restrict__ Add,
               const float* __restrict__ h, const float* __restrict__ g_,
               float* __restrict__ out, int N) {
    constexpr int GR  = 16;             // coarse rows per group (32 out rows)
    constexpr int WR  = GR + 4;         // staged window rows (incl halo)
    constexpr int SW  = TW / 2 + 8;     // staged cols (16B-aligned rows)
    constexpr int SW4 = SW / 4;
    constexpr int NPP = WR * SW4;       // float4 items per plane
    constexpr int NT  = 4 * NPP;        // float4 items per window
    constexpr int NR  = (NT + 255) / 256;
    constexpr int KW  = TW / 8;

    __shared__ float buf[2][4][WR][SW];
    __shared__ float Sh[2 * GR][SW];
    __shared__ float Dh[2 * GR][SW];

    const int b     = blockIdx.z;
    const int strip = blockIdx.x;
    const int rb    = blockIdx.y;
    const int c0  = strip * (TW / 2);
    const int j0  = c0 - 4;
    const int nb  = rb * (G * GR);      // coarse row base of block
    const int w0  = strip * TW;
    const int tid = threadIdx.x;
    const int M   = 2 * N;

    float hk[2][TAPS], gk[2][TAPS];     // hk[p][t] = h[8-2t+p]
#pragma unroll
    for (int t = 0; t < TAPS; ++t) {
        hk[0][t] = h[8 - 2 * t]; hk[1][t] = h[9 - 2 * t];
        gk[0][t] = g_[8 - 2 * t]; gk[1][t] = g_[9 - 2 * t];
    }

    const size_t plane = (size_t)N * N;
    const float* P0 = Ass + (size_t)b * plane;
    const float* P1 = Asd + (size_t)b * plane;
    const float* P2 = Ads + (size_t)b * plane;
    const float* P3 = Add + (size_t)b * plane;

    auto load_window = [&](int gi, float4* rg) {
        const int m0w = nb + gi * GR - 2;
        const bool interior = (m0w >= 0) && (m0w + WR <= N) && (j0 >= 0) && (j0 + SW <= N);
        if (interior) {
#pragma unroll
            for (int k = 0; k < NR; ++k) {
                const int e = tid + 256 * k;
                if (e < NT) {
                    const int q  = e / NPP;
                    const int rm = e - q * NPP;
                    const int r  = rm / SW4;
                    const int fc = rm - r * SW4;
                    const float* p = P0;
                    if (q == 1) p = P1; else if (q == 2) p = P2; else if (q == 3) p = P3;
                    rg[k] = *reinterpret_cast<const float4*>(p + (size_t)(m0w + r) * N + j0 + 4 * fc);
                }
            }
        } else {
#pragma unroll
            for (int k = 0; k < NR; ++k) {
                const int e = tid + 256 * k;
                if (e < NT) {
                    const int q  = e / NPP;
                    const int rm = e - q * NPP;
                    const int r  = rm / SW4;
                    const int fc = rm - r * SW4;
                    const float* p = P0;
                    if (q == 1) p = P1; else if (q == 2) p = P2; else if (q == 3) p = P3;
                    float4 v;
                    v.x = ldrc(p, m0w + r, j0 + 4 * fc + 0, N);
                    v.y = ldrc(p, m0w + r, j0 + 4 * fc + 1, N);
                    v.z = ldrc(p, m0w + r, j0 + 4 * fc + 2, N);
                    v.w = ldrc(p, m0w + r, j0 + 4 * fc + 3, N);
                    rg[k] = v;
                }
            }
        }
    };
    auto write_window = [&](int sl, const float4* rg) {
#pragma unroll
        for (int k = 0; k < NR; ++k) {
            const int e = tid + 256 * k;
            if (e < NT) {
                const int q  = e / NPP;
                const int rm = e - q * NPP;
                const int r  = rm / SW4;
                const int fc = rm - r * SW4;
                *reinterpret_cast<float4*>(&buf[sl][q][r][4 * fc]) = rg[k];
            }
        }
    };

    float4 rg[NR];
    load_window(0, rg);
    write_window(0, rg);
    barrier_lgkm();

    for (int gi = 0; gi < G; ++gi) {
        const int sl = gi & 1;
        if (gi + 1 < G) load_window(gi + 1, rg);   // A: prefetch into regs

        // B: vertical synthesis from buf[sl] -> Sh/Dh
        for (int e = tid; e < GR * SW4; e += 256) {
            const int nl = e / SW4;
            const int fc = (e - nl * SW4) * 4;
            float4 s0 = {0,0,0,0}, s1 = {0,0,0,0}, d0 = {0,0,0,0}, d1 = {0,0,0,0};
#pragma unroll
            for (int t = 0; t < TAPS; ++t) {
                const float4 va = *reinterpret_cast<const float4*>(&buf[sl][0][nl + t][fc]);
                const float4 vb = *reinterpret_cast<const float4*>(&buf[sl][1][nl + t][fc]);
                const float4 vc = *reinterpret_cast<const float4*>(&buf[sl][2][nl + t][fc]);
                const float4 vd = *reinterpret_cast<const float4*>(&buf[sl][3][nl + t][fc]);
                fma4(s0, hk[0][t], va); fma4(s0, gk[0][t], vb);
                fma4(s1, hk[1][t], va); fma4(s1, gk[1][t], vb);
                fma4(d0, hk[0][t], vc); fma4(d0, gk[0][t], vd);
                fma4(d1, hk[1][t], vc); fma4(d1, gk[1][t], vd);
            }
            *reinterpret_cast<float4*>(&Sh[2 * nl][fc])     = s0;
            *reinterpret_cast<float4*>(&Sh[2 * nl + 1][fc]) = s1;
            *reinterpret_cast<float4*>(&Dh[2 * nl][fc])     = d0;
            *reinterpret_cast<float4*>(&Dh[2 * nl + 1][fc]) = d1;
        }
        barrier_lgkm();                            // C: no vmcnt drain

        // D: horizontal synthesis + store (one item per thread)
        for (int e = tid; e < 2 * GR * KW; e += 256) {
            const int r = e / KW;
            const int u = e - r * KW;
            float sv[12], dv[12];
            *reinterpret_cast<float4*>(&sv[0]) = *reinterpret_cast<const float4*>(&Sh[r][4 * u]);
            *reinterpret_cast<float4*>(&sv[4]) = *reinterpret_cast<const float4*>(&Sh[r][4 * u + 4]);
            *reinterpret_cast<float4*>(&sv[8]) = *reinterpret_cast<const float4*>(&Sh[r][4 * u + 8]);
            *reinterpret_cast<float4*>(&dv[0]) = *reinterpret_cast<const float4*>(&Dh[r][4 * u]);
            *reinterpret_cast<float4*>(&dv[4]) = *reinterpret_cast<const float4*>(&Dh[r][4 * u + 4]);
            *reinterpret_cast<float4*>(&dv[8]) = *reinterpret_cast<const float4*>(&Dh[r][4 * u + 8]);
            float o[8];
#pragma unroll
            for (int cc = 0; cc < 4; ++cc) {
                float o0 = 0.f, o1 = 0.f;
#pragma unroll
                for (int t = 0; t < TAPS; ++t) {
                    const float sx = sv[cc + t + 2], dx = dv[cc + t + 2];
                    o0 += hk[0][t] * sx + gk[0][t] * dx;
                    o1 += hk[1][t] * sx + gk[1][t] * dx;
                }
                o[2 * cc] = o0; o[2 * cc + 1] = o1;
            }
            const int orow = 2 * (nb + gi * GR) + r;
            float* dst = out + ((size_t)b * M + orow) * M + w0 + 8 * u;
            *reinterpret_cast<float4*>(dst)     = make_float4(o[0], o[1], o[2], o[3]);
            *reinterpret_cast<float4*>(dst + 4) = make_float4(o[4], o[5], o[6], o[7]);
        }

        if (gi + 1 < G) write_window(sl ^ 1, rg);  // E: commit prefetch (waits vmcnt here)
        barrier_lgkm();                            // F
    }
}

// ---------------- small fused kernel (level 2) ----------------
template<int TH, int TW>
__global__ __launch_bounds__(256)
void idwt_fused(const float* __restrict__ Ass, const float* __restrict__ Asd,
                const float* __restrict__ Ads, const float* __restrict__ Add,
                const float* __restrict__ h, const float* __restrict__ g,
                float* __restrict__ out, int N) {
    constexpr int THc = TH / 2;
    constexpr int SW  = TW / 2 + 8;
    constexpr int SW4 = SW / 4;
    constexpr int RH  = THc + 4;
    __shared__ float Ain[4][RH][SW];
    __shared__ float Sh[TH][SW];
    __shared__ float Dh[TH][SW];

    const int b  = blockIdx.z;
    const int r0 = blockIdx.y * TH;
    const int w0 = blockIdx.x * TW;
    const int n0 = r0 >> 1;
    const int c0 = w0 >> 1;
    const int m0 = n0 - 2;
    const int j0 = c0 - 4;
    const int tid = threadIdx.x;

    float hk[2][TAPS], gk[2][TAPS];
#pragma unroll
    for (int t = 0; t < TAPS; ++t) {
        hk[0][t] = h[8 - 2 * t]; hk[1][t] = h[9 - 2 * t];
        gk[0][t] = g[8 - 2 * t]; gk[1][t] = g[9 - 2 * t];
    }

    const size_t plane = (size_t)N * N;
    const bool interior = (n0 >= 2) && (n0 + THc + 2 <= N) && (c0 >= 4) && (c0 + TW / 2 + 4 <= N);
    if (interior) {
#pragma unroll
        for (int q = 0; q < 4; ++q) {
            const float* __restrict__ p =
                ((q == 0) ? Ass : (q == 1) ? Asd : (q == 2) ? Ads : Add) + (size_t)b * plane;
            const float* __restrict__ base = p + (size_t)m0 * N + j0;
            for (int e = tid; e < RH * SW4; e += 256) {
                const int r  = e / SW4;
                const int fc = e - r * SW4;
                *reinterpret_cast<float4*>(&Ain[q][r][4 * fc]) =
                    *reinterpret_cast<const float4*>(base + (size_t)r * N + 4 * fc);
            }
        }
    } else {
#pragma unroll
        for (int q = 0; q < 4; ++q) {
            const float* __restrict__ p =
                ((q == 0) ? Ass : (q == 1) ? Asd : (q == 2) ? Ads : Add) + (size_t)b * plane;
            for (int e = tid; e < RH * SW; e += 256) {
                const int r = e / SW;
                const int k = e - r * SW;
                Ain[q][r][k] = ldrc(p, m0 + r, j0 + k, N);
            }
        }
    }
    __syncthreads();

    for (int e = tid; e < THc * SW4; e += 256) {
        const int nl = e / SW4;
        const int fc = (e - nl * SW4) * 4;
        float4 s0 = {0,0,0,0}, s1 = {0,0,0,0}, d0 = {0,0,0,0}, d1 = {0,0,0,0};
#pragma unroll
        for (int t = 0; t < TAPS; ++t) {
            const float4 va = *reinterpret_cast<const float4*>(&Ain[0][nl + t][fc]);
            const float4 vb = *reinterpret_cast<const float4*>(&Ain[1][nl + t][fc]);
            const float4 vc = *reinterpret_cast<const float4*>(&Ain[2][nl + t][fc]);
            const float4 vd = *reinterpret_cast<const float4*>(&Ain[3][nl + t][fc]);
            fma4(s0, hk[0][t], va); fma4(s0, gk[0][t], vb);
            fma4(s1, hk[1][t], va); fma4(s1, gk[1][t], vb);
            fma4(d0, hk[0][t], vc); fma4(d0, gk[0][t], vd);
            fma4(d1, hk[1][t], vc); fma4(d1, gk[1][t], vd);
        }
        *reinterpret_cast<float4*>(&Sh[2 * nl][fc])     = s0;
        *reinterpret_cast<float4*>(&Sh[2 * nl + 1][fc]) = s1;
        *reinterpret_cast<float4*>(&Dh[2 * nl][fc])     = d0;
        *reinterpret_cast<float4*>(&Dh[2 * nl + 1][fc]) = d1;
    }
    __syncthreads();

    const int M = 2 * N;
    constexpr int KW = TW / 8;
    for (int e = tid; e < TH * KW; e += 256) {
        const int r = e / KW;
        const int u = e - r * KW;
        float sv[12], dv[12];
        *reinterpret_cast<float4*>(&sv[0]) = *reinterpret_cast<const float4*>(&Sh[r][4 * u]);
        *reinterpret_cast<float4*>(&sv[4]) = *reinterpret_cast<const float4*>(&Sh[r][4 * u + 4]);
        *reinterpret_cast<float4*>(&sv[8]) = *reinterpret_cast<const float4*>(&Sh[r][4 * u + 8]);
        *reinterpret_cast<float4*>(&dv[0]) = *reinterpret_cast<const float4*>(&Dh[r][4 * u]);
        *reinterpret_cast<float4*>(&dv[4]) = *reinterpret_cast<const float4*>(&Dh[r][4 * u + 4]);
        *reinterpret_cast<float4*>(&dv[8]) = *reinterpret_cast<const float4*>(&Dh[r][4 * u + 8]);
        float o[8];
#pragma unroll
        for (int cc = 0; cc < 4; ++cc) {
            float o0 = 0.f, o1 = 0.f;
#pragma unroll
            for (int t = 0; t < TAPS; ++t) {
                const float sx = sv[cc + t + 2], dx = dv[cc + t + 2];
                o0 += hk[0][t] * sx + gk[0][t] * dx;
                o1 += hk[1][t] * sx + gk[1][t] * dx;
            }
            o[2 * cc] = o0; o[2 * cc + 1] = o1;
        }
        float* dst = out + ((size_t)b * M + (r0 + r)) * M + w0 + 8 * u;
        *reinterpret_cast<float4*>(dst)     = make_float4(o[0], o[1], o[2], o[3]);
        *reinterpret_cast<float4*>(dst + 4) = make_float4(o[4], o[5], o[6], o[7]);
    }
}

extern "C" void kernel_launch(void* const* d_in, const int* in_sizes, int n_in,
                              void* d_out, int out_size, void* d_ws, size_t ws_size,
                              hipStream_t stream) {
    const float* ss = (const float*)d_in[0];
    const float* sd[3] = {(const float*)d_in[1], (const float*)d_in[2], (const float*)d_in[3]};
    const float* ds[3] = {(const float*)d_in[4], (const float*)d_in[5], (const float*)d_in[6]};
    const float* dd[3] = {(const float*)d_in[7], (const float*)d_in[8], (const float*)d_in[9]};
    const float* h = (const float*)d_in[10];
    const float* g = (const float*)d_in[11];
    float* out = (float*)d_out;

    char* ws = (char*)d_ws;
    float* I0 = (float*)ws;                        // level-2 output (2 MiB)
    float* I1 = (float*)(ws + ((size_t)2 << 20));  // level-1 output (8 MiB)

    // level 2: 128 -> 256 (small fused kernel)
    {
        const int N = 128;
        dim3 grid(256 / 32, 256 / 16, NB);
        idwt_fused<16, 32><<<grid, 256, 0, stream>>>(ss, sd[2], ds[2], dd[2], h, g, I0, N);
    }
    // level 1: 256 -> 512 (pipelined, G=2 -> 64 out rows/block)
    {
        const int N = 256;
        dim3 grid(512 / 64, 512 / 64, NB);         // strips, row-blocks, batch
        idwt_pipe<64, 2><<<grid, 256, 0, stream>>>(I0, sd[1], ds[1], dd[1], h, g, I1, N);
    }
    // level 0: 512 -> 1024 (pipelined, G=4 -> 128 out rows/block)
    {
        const int N = 512;
        dim3 grid(1024 / 64, 1024 / 128, NB);
        idwt_pipe<64, 4><<<grid, 256, 0, stream>>>(I1, sd[0], ds[0], dd[0], h, g, out, N);
    }
}

// Round 7
// 53.286 us; speedup vs baseline: 2.0428x; 2.0428x over previous
//
#include <hip/hip_runtime.h>

#define NB 8
#define TAPS 5

// Barrier-free, LDS-free direct IDWT level kernel.
// Thread = (b, coarse row n, 4 coarse cols). Produces 2x8 output patch.
// Row antireflect folded into tap coefficients (clamped row window).
// Col antireflect applied as a post-vertical register remap (clamped col base).
__global__ __launch_bounds__(256)
void idwt_direct(const float* __restrict__ Pss, const float* __restrict__ Psd,
                 const float* __restrict__ Pds, const float* __restrict__ Pdd,
                 const float* __restrict__ h, const float* __restrict__ g_,
                 float* __restrict__ out, int N) {
    const int NJ = N >> 2;
    const int total = NB * N * NJ;
    const int tid = blockIdx.x * blockDim.x + threadIdx.x;
    if (tid >= total) return;
    const int jc = tid % NJ;
    const int rest = tid / NJ;
    const int n = rest % N;
    const int b = rest / N;

    float hk[2][TAPS], gk[2][TAPS];          // hk[p][t] = h[8-2t+p] (flipped polyphase)
#pragma unroll
    for (int t = 0; t < TAPS; ++t) {
        hk[0][t] = h[8 - 2 * t]; hk[1][t] = h[9 - 2 * t];
        gk[0][t] = g_[8 - 2 * t]; gk[1][t] = g_[9 - 2 * t];
    }

    // ---- row-reflect -> coefficient vectors over 5 physical rows pb..pb+4
    int pb = n - 2;
    if (pb < 0) pb = 0;
    if (pb > N - 5) pb = N - 5;
    float C0[5], C1[5], G0[5], G1[5];
    if (n >= 2 && n <= N - 3) {              // wave-uniform for NJ>=64 mappings
#pragma unroll
        for (int t = 0; t < TAPS; ++t) {
            C0[t] = hk[0][t]; C1[t] = hk[1][t];
            G0[t] = gk[0][t]; G1[t] = gk[1][t];
        }
    } else {
#pragma unroll
        for (int t = 0; t < TAPS; ++t) { C0[t] = 0.f; C1[t] = 0.f; G0[t] = 0.f; G1[t] = 0.f; }
#pragma unroll
        for (int t = 0; t < TAPS; ++t) {
            const int m = n - 2 + t;
            int i1, i2; float w1, w2;
            if (m < 0)        { i1 = 0 - pb;        w1 = 2.f; i2 = -m - pb;               w2 = -1.f; }
            else if (m >= N)  { i1 = (N - 1) - pb;  w1 = 2.f; i2 = 2 * (N - 1) - m - pb;  w2 = -1.f; }
            else              { i1 = m - pb;        w1 = 1.f; i2 = m - pb;                w2 = 0.f;  }
#pragma unroll
            for (int r = 0; r < 5; ++r) {
                const float w = ((r == i1) ? w1 : 0.f) + ((r == i2) ? w2 : 0.f);
                C0[r] += w * hk[0][t]; C1[r] += w * hk[1][t];
                G0[r] += w * gk[0][t]; G1[r] += w * gk[1][t];
            }
        }
    }

    // ---- clamped column window: logical cols jb..jb+7, physical base..base+7
    const int jb = 4 * jc - 2;
    int base = jb;
    if (base < 0) base = 0;
    if (base > N - 8) base = N - 8;

    const size_t plane = (size_t)N * N;
    const float* r0 = Pss + (size_t)b * plane + (size_t)pb * N + base;
    const float* r1 = Psd + (size_t)b * plane + (size_t)pb * N + base;
    const float* r2 = Pds + (size_t)b * plane + (size_t)pb * N + base;
    const float* r3 = Pdd + (size_t)b * plane + (size_t)pb * N + base;

    float s0[8], s1[8], d0[8], d1[8];
#pragma unroll
    for (int k = 0; k < 8; ++k) { s0[k] = 0.f; s1[k] = 0.f; d0[k] = 0.f; d1[k] = 0.f; }

    // ---- vertical synthesis: 5 physical rows x 4 planes, uniform float2 loads
#pragma unroll
    for (int r = 0; r < 5; ++r) {
        float a[8], bq[8], c[8], dq[8];
#pragma unroll
        for (int k = 0; k < 4; ++k) {
            const float2 va = *reinterpret_cast<const float2*>(r0 + 2 * k);
            const float2 vb = *reinterpret_cast<const float2*>(r1 + 2 * k);
            const float2 vc = *reinterpret_cast<const float2*>(r2 + 2 * k);
            const float2 vd = *reinterpret_cast<const float2*>(r3 + 2 * k);
            a[2 * k] = va.x;  a[2 * k + 1] = va.y;
            bq[2 * k] = vb.x; bq[2 * k + 1] = vb.y;
            c[2 * k] = vc.x;  c[2 * k + 1] = vc.y;
            dq[2 * k] = vd.x; dq[2 * k + 1] = vd.y;
        }
#pragma unroll
        for (int k = 0; k < 8; ++k) {
            s0[k] += C0[r] * a[k] + G0[r] * bq[k];
            s1[k] += C1[r] * a[k] + G1[r] * bq[k];
            d0[k] += C0[r] * c[k] + G0[r] * dq[k];
            d1[k] += C1[r] * c[k] + G1[r] * dq[k];
        }
        r0 += N; r1 += N; r2 += N; r3 += N;
    }

    // ---- column antireflect remap (edge lanes only; exact by linearity)
    if (jb < 0) {                            // left edge: logical[k] = phys[k-2], heads reflected
#pragma unroll
        for (int q = 0; q < 4; ++q) {
            float* A = (q == 0) ? s0 : (q == 1) ? s1 : (q == 2) ? d0 : d1;
            const float o0 = A[0], o1 = A[1], o2 = A[2];
#pragma unroll
            for (int k = 7; k >= 2; --k) A[k] = A[k - 2];
            A[1] = 2.f * o0 - o1;
            A[0] = 2.f * o0 - o2;
        }
    } else if (jb > base) {                  // right edge: logical[k] = phys[k+2], tails reflected
#pragma unroll
        for (int q = 0; q < 4; ++q) {
            float* A = (q == 0) ? s0 : (q == 1) ? s1 : (q == 2) ? d0 : d1;
            const float o5 = A[5], o6 = A[6], o7 = A[7];
#pragma unroll
            for (int k = 0; k < 6; ++k) A[k] = A[k + 2];
            A[6] = 2.f * o7 - o6;
            A[7] = 2.f * o7 - o5;
        }
    }

    // ---- horizontal synthesis: 4 output pairs x 2 rows
    const int M = 2 * N;
    float oa[8], ob[8];
#pragma unroll
    for (int cc = 0; cc < 4; ++cc) {
        float x0 = 0.f, x1 = 0.f, y0 = 0.f, y1 = 0.f;
#pragma unroll
        for (int t = 0; t < TAPS; ++t) {
            const float sA = s0[cc + t], dA = d0[cc + t];
            const float sB = s1[cc + t], dB = d1[cc + t];
            x0 += hk[0][t] * sA + gk[0][t] * dA;
            x1 += hk[1][t] * sA + gk[1][t] * dA;
            y0 += hk[0][t] * sB + gk[0][t] * dB;
            y1 += hk[1][t] * sB + gk[1][t] * dB;
        }
        oa[2 * cc] = x0; oa[2 * cc + 1] = x1;
        ob[2 * cc] = y0; ob[2 * cc + 1] = y1;
    }

    float* dst0 = out + ((size_t)b * M + 2 * n) * M + 8 * jc;
    float* dst1 = dst0 + M;
    *reinterpret_cast<float4*>(dst0)     = make_float4(oa[0], oa[1], oa[2], oa[3]);
    *reinterpret_cast<float4*>(dst0 + 4) = make_float4(oa[4], oa[5], oa[6], oa[7]);
    *reinterpret_cast<float4*>(dst1)     = make_float4(ob[0], ob[1], ob[2], ob[3]);
    *reinterpret_cast<float4*>(dst1 + 4) = make_float4(ob[4], ob[5], ob[6], ob[7]);
}

extern "C" void kernel_launch(void* const* d_in, const int* in_sizes, int n_in,
                              void* d_out, int out_size, void* d_ws, size_t ws_size,
                              hipStream_t stream) {
    const float* ss = (const float*)d_in[0];
    const float* sd[3] = {(const float*)d_in[1], (const float*)d_in[2], (const float*)d_in[3]};
    const float* ds[3] = {(const float*)d_in[4], (const float*)d_in[5], (const float*)d_in[6]};
    const float* dd[3] = {(const float*)d_in[7], (const float*)d_in[8], (const float*)d_in[9]};
    const float* h = (const float*)d_in[10];
    const float* g = (const float*)d_in[11];
    float* out = (float*)d_out;

    char* ws = (char*)d_ws;
    float* I0 = (float*)ws;                        // level-2 output (2 MiB)
    float* I1 = (float*)(ws + ((size_t)2 << 20));  // level-1 output (8 MiB)

    auto launch = [&](const float* a, const float* sdp, const float* dsp, const float* ddp,
                      float* dst, int N) {
        const int total = NB * N * (N >> 2);
        idwt_direct<<<(total + 255) / 256, 256, 0, stream>>>(a, sdp, dsp, ddp, h, g, dst, N);
    };

    launch(ss, sd[2], ds[2], dd[2], I0, 128);   // level 2: 128 -> 256
    launch(I0, sd[1], ds[1], dd[1], I1, 256);   // level 1: 256 -> 512
    launch(I1, sd[0], ds[0], dd[0], out, 512);  // level 0: 512 -> 1024
}